// Round 7
// baseline (2041.228 us; speedup 1.0000x reference)
//
#include <hip/hip_runtime.h>
#include <hip/hip_bf16.h>

constexpr int U_N = 100000;
constexpr int I_N = 50000;
constexpr int KDIM = 64;
constexpr float EPSF = 1e-12f;

// binning constants: bins of 1024 rows, 40-deep LDS staging per bin
constexpr int RBIN_LOG = 10;
constexpr int NB_MAX = 147;     // ceil(150000/1024)
constexpr int STG = 40;

typedef float f4 __attribute__((ext_vector_type(4)));
typedef unsigned short u16;

__device__ inline f4 ld4(const float* p) { return *(const f4*)p; }

// pack two f32 -> two bf16 (RNE) in one uint32
__device__ inline unsigned pack_bf16(float a, float b) {
    unsigned ua = __float_as_uint(a);
    unsigned ub = __float_as_uint(b);
    ua += 0x7fffu + ((ua >> 16) & 1u);
    ub += 0x7fffu + ((ub >> 16) & 1u);
    return (ua >> 16) | (ub & 0xffff0000u);
}

// unpack 8 bf16 (uint4) -> 8 f32
__device__ inline void bf8_to_f32(uint4 u, float* f) {
    unsigned w0 = u.x, w1 = u.y, w2 = u.z, w3 = u.w;
    f[0] = __uint_as_float(w0 << 16);  f[1] = __uint_as_float(w0 & 0xffff0000u);
    f[2] = __uint_as_float(w1 << 16);  f[3] = __uint_as_float(w1 & 0xffff0000u);
    f[4] = __uint_as_float(w2 << 16);  f[5] = __uint_as_float(w2 & 0xffff0000u);
    f[6] = __uint_as_float(w3 << 16);  f[7] = __uint_as_float(w3 & 0xffff0000u);
}

// ---------------- row CSR offsets ----------------

__global__ void hist_k4(const int* __restrict__ dst, int* __restrict__ deg, int E) {
    int i = (blockIdx.x * blockDim.x + threadIdx.x) * 4;
    if (i + 4 <= E) {
        int4 d = *(const int4*)(dst + i);
        atomicAdd(&deg[d.x], 1);
        atomicAdd(&deg[d.y], 1);
        atomicAdd(&deg[d.z], 1);
        atomicAdd(&deg[d.w], 1);
    } else {
        for (int k = i; k < E; ++k) atomicAdd(&deg[dst[k]], 1);
    }
}

__global__ void scan_partial(const int* __restrict__ deg, int* __restrict__ sums, int n) {
    __shared__ int red[256];
    int b = blockIdx.x, t = threadIdx.x;
    int base = b * 1024;
    int s = 0;
    for (int j = t; j < 1024; j += 256) {
        int i = base + j;
        s += (i < n) ? deg[i] : 0;
    }
    red[t] = s;
    __syncthreads();
    for (int o = 128; o > 0; o >>= 1) {
        if (t < o) red[t] += red[t + o];
        __syncthreads();
    }
    if (t == 0) sums[b] = red[0];
}

__global__ void scan_sums_k(int* __restrict__ sums, int nb) {
    __shared__ int a[256], b2[256];
    int t = threadIdx.x;
    int v = (t < nb) ? sums[t] : 0;
    a[t] = v;
    __syncthreads();
    int* cur = a; int* alt = b2;
    for (int o = 1; o < 256; o <<= 1) {
        int x = cur[t] + ((t >= o) ? cur[t - o] : 0);
        alt[t] = x;
        __syncthreads();
        int* tp = cur; cur = alt; alt = tp;
    }
    if (t < nb) sums[t] = cur[t] - v;   // exclusive
}

__global__ void scan_final(const int* __restrict__ deg, const int* __restrict__ sums,
                           int* __restrict__ start, int* __restrict__ pos, int n) {
    __shared__ int a[256], b2[256];
    int b = blockIdx.x, t = threadIdx.x;
    int base = b * 1024 + t * 4;
    int d[4];
#pragma unroll
    for (int j = 0; j < 4; ++j) d[j] = (base + j < n) ? deg[base + j] : 0;
    int tsum = d[0] + d[1] + d[2] + d[3];
    a[t] = tsum;
    __syncthreads();
    int* cur = a; int* alt = b2;
    for (int o = 1; o < 256; o <<= 1) {
        int x = cur[t] + ((t >= o) ? cur[t - o] : 0);
        alt[t] = x;
        __syncthreads();
        int* tp = cur; cur = alt; alt = tp;
    }
    int run = cur[t] - tsum + sums[b];
#pragma unroll
    for (int j = 0; j < 4; ++j) {
        if (base + j <= n) start[base + j] = run;   // also writes start[n] = total
        if (base + j < n)  pos[base + j] = run;
        run += d[j];
    }
}

// ---------------- binned CSR fill ----------------

// exclusive scan of 8-aligned bin sizes (NB <= 256); sizes derived from row start[]
__global__ void bin_scan(const int* __restrict__ start, int* __restrict__ gbase,
                         int* __restrict__ gpos, int NB, int nrows) {
    __shared__ int a[256], b2[256];
    int t = threadIdx.x;
    int sz = 0;
    if (t < NB) {
        int r0 = t << RBIN_LOG;
        int r1 = min(r0 + (1 << RBIN_LOG), nrows);
        sz = (start[r1] - start[r0] + 7) & ~7;
    }
    a[t] = sz;
    __syncthreads();
    int* cur = a; int* alt = b2;
    for (int o = 1; o < 256; o <<= 1) {
        int x = cur[t] + ((t >= o) ? cur[t - o] : 0);
        alt[t] = x;
        __syncthreads();
        int* tp = cur; cur = alt; alt = tp;
    }
    if (t < NB) {
        int ex = cur[t] - sz;   // exclusive
        gbase[t] = ex;
        gpos[t] = ex;
    }
}

// Phase A: stream edges, stage per-bin in LDS, flush full 8-groups as 64B stores.
// Edge packed as {src | dlow<<18, w_bits}; NIT*1024 edges per chunk.
template <int NIT>
__global__ void bin_edges(const int* __restrict__ src, const int* __restrict__ dst,
                          const float* __restrict__ w, int* __restrict__ gpos,
                          int2* __restrict__ tmp, int E, int NB) {
    __shared__ int2 stage[NB_MAX * STG];
    __shared__ int scnt[NB_MAX];
    const int tid = threadIdx.x;           // 0..1023
    for (int i = tid; i < NB; i += 1024) scnt[i] = 0;
    __syncthreads();

    const int nwg = gridDim.x;
    const int seg = (E + nwg - 1) / nwg;
    const int s0 = blockIdx.x * seg;
    const int s1 = min(E, s0 + seg);
    const int wid = tid >> 6, lane = tid & 63;

    for (int cb = s0; cb < s1; cb += NIT * 1024) {
        int2 vals[NIT];
        int bs[NIT];
        bool ok[NIT];
#pragma unroll
        for (int it = 0; it < NIT; ++it) {
            int idx = cb + it * 1024 + tid;
            ok[it] = idx < s1;
            if (ok[it]) {
                int d = dst[idx];
                int s = src[idx];
                float wt = w[idx];
                bs[it] = d >> RBIN_LOG;
                vals[it] = make_int2(s | ((d & ((1 << RBIN_LOG) - 1)) << 18),
                                     __float_as_int(wt));
            }
        }
#pragma unroll
        for (int it = 0; it < NIT; ++it) {
            if (ok[it]) {
                int b = bs[it];
                int slot = atomicAdd(&scnt[b], 1);
                if (slot < STG) {
                    stage[b * STG + slot] = vals[it];
                } else {                      // rare overflow: direct scatter
                    atomicSub(&scnt[b], 1);
                    int p = atomicAdd(&gpos[b], 1);
                    tmp[p] = vals[it];
                }
            }
        }
        __syncthreads();
        // flush full 8-groups; wave wid owns bins wid, wid+16, ...
        for (int b = wid; b < NB; b += 16) {
            int c = scnt[b];
            int nf = c & ~7;
            if (nf) {
                int p0;
                if (lane == 0) p0 = atomicAdd(&gpos[b], nf);
                p0 = __shfl(p0, 0, 64);
                if (lane < nf) tmp[p0 + lane] = stage[b * STG + lane];
                int rem = c - nf;
                int2 v;
                if (lane < rem) v = stage[b * STG + nf + lane];
                if (lane < rem) stage[b * STG + lane] = v;
                if (lane == 0) scnt[b] = rem;
            }
        }
        __syncthreads();
    }
    // drain partials
    for (int b = wid; b < NB; b += 16) {
        int c = scnt[b];
        if (c) {
            int p0;
            if (lane == 0) p0 = atomicAdd(&gpos[b], c);
            p0 = __shfl(p0, 0, 64);
            if (lane < c) tmp[p0 + lane] = stage[b * STG + lane];
        }
    }
}

// Phase B: one wg per bin; scatter bin's edges into final CSR (L2-local region).
__global__ void bin_scatter(const int2* __restrict__ tmp, const int* __restrict__ gbase,
                            const int* __restrict__ start, int* __restrict__ pos,
                            int2* __restrict__ e2, int nrows) {
    int b = blockIdx.x;
    int r0 = b << RBIN_LOG;
    int r1 = min(r0 + (1 << RBIN_LOG), nrows);
    int n = start[r1] - start[r0];
    int base = gbase[b];
    for (int i = threadIdx.x; i < n; i += blockDim.x) {
        int2 v = tmp[base + i];
        int s = v.x & 0x3FFFF;
        int d = r0 + (v.x >> 18);
        int p = atomicAdd(&pos[d], 1);
        e2[p] = make_int2(s, v.y);
    }
}

// ---------------- compute ----------------

__device__ inline float group8_sum(float v) {
    v += __shfl_xor(v, 1, 64);
    v += __shfl_xor(v, 2, 64);
    v += __shfl_xor(v, 4, 64);
    return v;
}

// Gather-accumulate one CSR row from bf16 table.
// g = lane>>3 (8 edge slots), l = lane&7 (8 feats each, 16B load); unroll x2.
__device__ inline void spmm_row_bf(const int2* __restrict__ e2, int j0, int j1,
                                   const u16* __restrict__ x, int g, int l,
                                   float a[8]) {
    float a0[8] = {0, 0, 0, 0, 0, 0, 0, 0};
    float a1[8] = {0, 0, 0, 0, 0, 0, 0, 0};
    int j = j0;
    for (; j + 16 <= j1; j += 16) {
        int2 ea = e2[j + g];
        int2 eb = e2[j + 8 + g];
        uint4 ua = *(const uint4*)(x + (size_t)ea.x * KDIM + l * 8);
        uint4 ub = *(const uint4*)(x + (size_t)eb.x * KDIM + l * 8);
        float wa = __int_as_float(ea.y), wb = __int_as_float(eb.y);
        float fa[8], fb[8];
        bf8_to_f32(ua, fa);
        bf8_to_f32(ub, fb);
#pragma unroll
        for (int c = 0; c < 8; ++c) {
            a0[c] += wa * fa[c];
            a1[c] += wb * fb[c];
        }
    }
    for (; j < j1; j += 8) {
        if (j + g < j1) {
            int2 ea = e2[j + g];
            uint4 ua = *(const uint4*)(x + (size_t)ea.x * KDIM + l * 8);
            float wa = __int_as_float(ea.y);
            float fa[8];
            bf8_to_f32(ua, fa);
#pragma unroll
            for (int c = 0; c < 8; ++c) a0[c] += wa * fa[c];
        }
    }
#pragma unroll
    for (int c = 0; c < 8; ++c) {
        float v = a0[c] + a1[c];
        v += __shfl_xor(v, 8, 64);
        v += __shfl_xor(v, 16, 64);
        v += __shfl_xor(v, 32, 64);
        a[c] = v;
    }
}

// cur(bf16) = acc(f32) = concat(Gu, Gi); one thread per 8 elements
__global__ void ego_init8(const float* __restrict__ Gu, const float* __restrict__ Gi,
                          u16* __restrict__ cur, float* __restrict__ acc, int n8) {
    int i = blockIdx.x * blockDim.x + threadIdx.x;
    if (i >= n8) return;
    const int nu8 = U_N * (KDIM / 8);
    const float* p = (i < nu8) ? Gu + (size_t)i * 8 : Gi + (size_t)(i - nu8) * 8;
    f4 v0 = ld4(p);
    f4 v1 = ld4(p + 4);
    uint4 pk;
    pk.x = pack_bf16(v0.x, v0.y);
    pk.y = pack_bf16(v0.z, v0.w);
    pk.z = pack_bf16(v1.x, v1.y);
    pk.w = pack_bf16(v1.z, v1.w);
    *(uint4*)(cur + (size_t)i * 8) = pk;
    *(f4*)(acc + (size_t)i * 8) = v0;
    *(f4*)(acc + (size_t)i * 8 + 4) = v1;
}

// f32 -> bf16 bulk convert, 8 elems/thread
__global__ void cvt_bf8(const float* __restrict__ in, u16* __restrict__ out, int n8) {
    int i = blockIdx.x * blockDim.x + threadIdx.x;
    if (i >= n8) return;
    f4 v0 = ld4(in + (size_t)i * 8);
    f4 v1 = ld4(in + (size_t)i * 8 + 4);
    uint4 pk;
    pk.x = pack_bf16(v0.x, v0.y);
    pk.y = pack_bf16(v0.z, v0.w);
    pk.z = pack_bf16(v1.x, v1.y);
    pk.w = pack_bf16(v1.z, v1.w);
    *(uint4*)(out + (size_t)i * 8) = pk;
}

// pull SPMM, bf16 in -> bf16 out (gis hop 1)
__global__ void spmm_pull_bf(const int* __restrict__ start, const int2* __restrict__ e2,
                             const u16* __restrict__ x, u16* __restrict__ y, int nrows) {
    const int lane = threadIdx.x & 63;
    const int g = lane >> 3, l = lane & 7;
    const int r = (blockIdx.x * blockDim.x + threadIdx.x) >> 6;
    if (r >= nrows) return;
    float a[8];
    spmm_row_bf(e2, start[r], start[r + 1], x, g, l, a);
    if (g == 0) {
        uint4 pk;
        pk.x = pack_bf16(a[0], a[1]);
        pk.y = pack_bf16(a[2], a[3]);
        pk.z = pack_bf16(a[4], a[5]);
        pk.w = pack_bf16(a[6], a[7]);
        *(uint4*)(y + (size_t)r * KDIM + l * 8) = pk;
    }
}

// pull SPMM, bf16 in -> f32 out (gis hop 2)
__global__ void spmm_pull_f32(const int* __restrict__ start, const int2* __restrict__ e2,
                              const u16* __restrict__ x, float* __restrict__ y, int nrows) {
    const int lane = threadIdx.x & 63;
    const int g = lane >> 3, l = lane & 7;
    const int r = (blockIdx.x * blockDim.x + threadIdx.x) >> 6;
    if (r >= nrows) return;
    float a[8];
    spmm_row_bf(e2, start[r], start[r + 1], x, g, l, a);
    if (g == 0) {
        float* yp = y + (size_t)r * KDIM + l * 8;
        *(f4*)yp = f4{a[0], a[1], a[2], a[3]};
        *(f4*)(yp + 4) = f4{a[4], a[5], a[6], a[7]};
    }
}

// pull SPMM + l2norm; normalized row -> cur (bf16), acc += normalized (f32)
__global__ void spmm_pull_norm(const int* __restrict__ start, const int2* __restrict__ e2,
                               const u16* __restrict__ x, u16* __restrict__ cur,
                               float* __restrict__ acc, int nrows) {
    const int lane = threadIdx.x & 63;
    const int g = lane >> 3, l = lane & 7;
    const int r = (blockIdx.x * blockDim.x + threadIdx.x) >> 6;
    if (r >= nrows) return;
    float a[8];
    spmm_row_bf(e2, start[r], start[r + 1], x, g, l, a);
    float loc = 0.f;
#pragma unroll
    for (int c = 0; c < 8; ++c) loc += a[c] * a[c];
    float ss = group8_sum(loc);
    float inv = 1.f / fmaxf(sqrtf(ss), EPSF);
    if (g == 0) {
        uint4 pk;
        pk.x = pack_bf16(a[0] * inv, a[1] * inv);
        pk.y = pack_bf16(a[2] * inv, a[3] * inv);
        pk.z = pack_bf16(a[4] * inv, a[5] * inv);
        pk.w = pack_bf16(a[6] * inv, a[7] * inv);
        *(uint4*)(cur + (size_t)r * KDIM + l * 8) = pk;
        float* ap = acc + (size_t)r * KDIM + l * 8;
        f4 o0 = ld4(ap);
        f4 o1 = ld4(ap + 4);
        o0 += f4{a[0] * inv, a[1] * inv, a[2] * inv, a[3] * inv};
        o1 += f4{a[4] * inv, a[5] * inv, a[6] * inv, a[7] * inv};
        *(f4*)ap = o0;
        *(f4*)(ap + 4) = o1;
    }
}

// Last UI layer fused with finalize
__global__ void spmm_pull_norm_final(const int* __restrict__ start, const int2* __restrict__ e2,
                                     const u16* __restrict__ x, const float* __restrict__ gis,
                                     float* __restrict__ acc_out, int nrows) {
    const int lane = threadIdx.x & 63;
    const int g = lane >> 3, l = lane & 7;
    const int r = (blockIdx.x * blockDim.x + threadIdx.x) >> 6;
    if (r >= nrows) return;
    float a[8];
    spmm_row_bf(e2, start[r], start[r + 1], x, g, l, a);
    float loc = 0.f;
#pragma unroll
    for (int c = 0; c < 8; ++c) loc += a[c] * a[c];
    float ss = group8_sum(loc);
    float inv = 1.f / fmaxf(sqrtf(ss), EPSF);
    if (g != 0) return;
    float* ap = acc_out + (size_t)r * KDIM + l * 8;
    f4 v0 = (ld4(ap) + f4{a[0] * inv, a[1] * inv, a[2] * inv, a[3] * inv}) * 0.25f;
    f4 v1 = (ld4(ap + 4) + f4{a[4] * inv, a[5] * inv, a[6] * inv, a[7] * inv}) * 0.25f;
    if (r >= U_N) {
        const float* gp = gis + (size_t)(r - U_N) * KDIM + l * 8;
        f4 g0 = ld4(gp);
        f4 g1 = ld4(gp + 4);
        float loc2 = g0.x * g0.x + g0.y * g0.y + g0.z * g0.z + g0.w * g0.w
                   + g1.x * g1.x + g1.y * g1.y + g1.z * g1.z + g1.w * g1.w;
        float ss2 = group8_sum(loc2);
        float inv2 = 1.f / fmaxf(sqrtf(ss2), EPSF);
        v0 += g0 * inv2;
        v1 += g1 * inv2;
    }
    *(f4*)ap = v0;
    *(f4*)(ap + 4) = v1;
}

extern "C" void kernel_launch(void* const* d_in, const int* in_sizes, int n_in,
                              void* d_out, int out_size, void* d_ws, size_t ws_size,
                              hipStream_t stream) {
    const float* Gu     = (const float*)d_in[0];
    const float* Gi     = (const float*)d_in[1];
    const float* Gis    = (const float*)d_in[2];
    const float* ii_w   = (const float*)d_in[3];
    const float* ui_w   = (const float*)d_in[4];
    const int*   ii_src = (const int*)d_in[5];
    const int*   ii_dst = (const int*)d_in[6];
    const int*   ui_src = (const int*)d_in[7];
    const int*   ui_dst = (const int*)d_in[8];
    const int E_II = in_sizes[5];
    const int E_UI = in_sizes[7];

    const int NR    = U_N + I_N;                     // 150000 rows
    const size_t NI = (size_t)I_N * KDIM;            // 3.2M elems
    const size_t NA = (size_t)NR * KDIM;             // 9.6M elems
    const int NB_UI = (NR + 1023) >> 10;             // 147
    const int NB_II = (I_N + 1023) >> 10;            // 49

    // ---- workspace layout ----
    u16*  bufA = (u16*)d_ws;               // NA bf16
    u16*  bufB = bufA + NA;                // NA bf16
    u16*  gis0 = bufB + NA;                // NI bf16
    u16*  gisA = gis0 + NI;                // NI bf16
    float* gisB = (float*)(gisA + NI);     // NI f32
    int2*  ui_e = (int2*)(gisB + NI);      // E_UI
    int2*  ii_e = ui_e + E_UI;             // E_II
    int*   ui_start = (int*)(ii_e + E_II); // NR+1
    int*   ui_pos   = ui_start + (NR + 1); // NR
    int*   ii_start = ui_pos + NR;         // I_N+1
    int*   ii_pos   = ii_start + (I_N + 1);// I_N
    int*   sums     = ii_pos + I_N;        // 256
    int*   gbaseU   = sums + 256;          // NB_UI
    int*   gposU    = gbaseU + NB_MAX;     // NB_UI
    int*   gbaseI   = gposU + NB_MAX;      // NB_II
    int*   gposI    = gbaseI + NB_MAX;     // NB_II

    // tmp (phase-A bucketed edges) aliases bufA/bufB/gis0 (dead during builds)
    int2* tmp = (int2*)d_ws;               // capacity E_UI + 8*NB ✓

    float* acc = (float*)d_out;

    const int nb_ui = (NR + 1023) / 1024;    // 147 (scan blocks)
    const int nb_ii = (I_N + 1023) / 1024;   // 49

    // ---- UI CSR ----
    hipMemsetAsync(ui_pos, 0, NR * sizeof(int), stream);
    hist_k4<<<(E_UI / 4 + 255) / 256, 256, 0, stream>>>(ui_dst, ui_pos, E_UI);
    scan_partial<<<nb_ui, 256, 0, stream>>>(ui_pos, sums, NR);
    scan_sums_k<<<1, 256, 0, stream>>>(sums, nb_ui);
    scan_final<<<nb_ui, 256, 0, stream>>>(ui_pos, sums, ui_start, ui_pos, NR);
    bin_scan<<<1, 256, 0, stream>>>(ui_start, gbaseU, gposU, NB_UI, NR);
    bin_edges<4><<<256, 1024, 0, stream>>>(ui_src, ui_dst, ui_w, gposU, tmp, E_UI, NB_UI);
    bin_scatter<<<NB_UI, 1024, 0, stream>>>(tmp, gbaseU, ui_start, ui_pos, ui_e, NR);

    // ---- II CSR ----
    hipMemsetAsync(ii_pos, 0, I_N * sizeof(int), stream);
    hist_k4<<<(E_II / 4 + 255) / 256, 256, 0, stream>>>(ii_dst, ii_pos, E_II);
    scan_partial<<<nb_ii, 256, 0, stream>>>(ii_pos, sums, I_N);
    scan_sums_k<<<1, 256, 0, stream>>>(sums, nb_ii);
    scan_final<<<nb_ii, 256, 0, stream>>>(ii_pos, sums, ii_start, ii_pos, I_N);
    bin_scan<<<1, 256, 0, stream>>>(ii_start, gbaseI, gposI, NB_II, I_N);
    bin_edges<1><<<256, 1024, 0, stream>>>(ii_src, ii_dst, ii_w, gposI, tmp, E_II, NB_II);
    bin_scatter<<<NB_II, 1024, 0, stream>>>(tmp, gbaseI, ii_start, ii_pos, ii_e, I_N);

    // ---- gis chain ----
    cvt_bf8<<<(int)((NI / 8 + 255) / 256), 256, 0, stream>>>(Gis, gis0, (int)(NI / 8));
    spmm_pull_bf<<<(I_N + 3) / 4, 256, 0, stream>>>(ii_start, ii_e, gis0, gisA, I_N);
    spmm_pull_f32<<<(I_N + 3) / 4, 256, 0, stream>>>(ii_start, ii_e, gisA, gisB, I_N);

    // ---- ego init ----
    ego_init8<<<(int)((NA / 8 + 255) / 256), 256, 0, stream>>>(Gu, Gi, bufA, acc, (int)(NA / 8));

    // ---- 3 UI layers ----
    spmm_pull_norm<<<(NR + 3) / 4, 256, 0, stream>>>(ui_start, ui_e, bufA, bufB, acc, NR);
    spmm_pull_norm<<<(NR + 3) / 4, 256, 0, stream>>>(ui_start, ui_e, bufB, bufA, acc, NR);
    spmm_pull_norm_final<<<(NR + 3) / 4, 256, 0, stream>>>(ui_start, ui_e, bufA, gisB, acc, NR);
}